// Round 2
// baseline (401.035 us; speedup 1.0000x reference)
//
#include <hip/hip_runtime.h>
#include <math.h>

typedef unsigned short u16;
typedef __bf16 bf16x8 __attribute__((ext_vector_type(8)));
typedef float f32x4 __attribute__((ext_vector_type(4)));
typedef short s16x8 __attribute__((ext_vector_type(8)));
typedef short s16x4 __attribute__((ext_vector_type(4)));

__device__ __forceinline__ float b2f(u16 u) {
    union { unsigned i; float f; } c; c.i = ((unsigned)u) << 16; return c.f;
}
__device__ __forceinline__ u16 f2b(float f) {
    union { float f; unsigned i; } c; c.f = f;
    return (u16)((c.i + 0x7fffu + ((c.i >> 16) & 1u)) >> 16);
}
__device__ __forceinline__ float gelu_f(float v) {
    return 0.5f * v * (1.0f + erff(v * 0.70710678118654752f));
}
__device__ __forceinline__ s16x8 cvt8(f32x4 a, f32x4 b) {
    s16x8 r;
    r[0] = (short)f2b(a[0]); r[1] = (short)f2b(a[1]);
    r[2] = (short)f2b(a[2]); r[3] = (short)f2b(a[3]);
    r[4] = (short)f2b(b[0]); r[5] = (short)f2b(b[1]);
    r[6] = (short)f2b(b[2]); r[7] = (short)f2b(b[3]);
    return r;
}

#define TILE_M 128
#define TILE_N 128
#define TILE_K 32

// C[m][n] = sum_k A[m][k]*W[n][k] + bias[n]. W/bias always f32 (model weights).
// A_F32: A is f32 (else bf16-as-u16). Two column-halves (half = bx>=halfBlocks)
// with separate A/W/bias/out. mode: 0 = bf16 linear out, 1 = f32 sigmoid out.
template<int A_F32>
__global__ __launch_bounds__(256, 2)
void gemm_bt(const void* __restrict__ A0v, const void* __restrict__ A1v,
             const float* __restrict__ W0, const float* __restrict__ W1,
             const float* __restrict__ B0, const float* __restrict__ B1,
             void* __restrict__ O0v, void* __restrict__ O1v,
             int lda, int K, int halfBlocks, int ldo0, int ldo1,
             int mode0, int mode1)
{
    __shared__ u16 sA[TILE_M * TILE_K];
    __shared__ u16 sW[TILE_N * TILE_K];

    const int bx = blockIdx.x, by = blockIdx.y;
    const int half = (bx >= halfBlocks) ? 1 : 0;
    const int bxl = bx - half * halfBlocks;
    const float* Wp = (half ? W1 : W0) + (size_t)bxl * TILE_N * K;
    const float* bias = (half ? B1 : B0) + bxl * TILE_N;
    void* outv = half ? O1v : O0v;
    const int ldo = half ? ldo1 : ldo0;
    const int mode = half ? mode1 : mode0;
    const float* Af = (const float*)(half ? A1v : A0v) + (size_t)by * TILE_M * lda;
    const u16*   Ab = (const u16*)(half ? A1v : A0v) + (size_t)by * TILE_M * lda;

    const int tid = threadIdx.x;
    const int lane = tid & 63;
    const int wave = tid >> 6;
    const int wm = (wave >> 1) * 64;
    const int wn = (wave & 1) * 64;
    const int fc = lane & 15;
    const int quad = lane >> 4;

    // 16B chunk p holds logical (row=p>>2, k8=((p&3)-(row>>1))&3); the inverse
    // placement row*4 + ((k8+(row>>1))&3) spreads the 16 frag-read lanes
    // across bank-slots (2-way aliasing = free per m136).
    const int p0 = tid, p1 = tid + 256;
    const int r0 = p0 >> 2, k80 = ((p0 & 3) - (r0 >> 1)) & 3;
    const int r1 = p1 >> 2, k81 = ((p1 & 3) - (r1 >> 1)) & 3;

    f32x4 acc[4][4];
#pragma unroll
    for (int i = 0; i < 4; ++i)
#pragma unroll
        for (int j = 0; j < 4; ++j)
            acc[i][j] = f32x4{0.f, 0.f, 0.f, 0.f};

    for (int k0 = 0; k0 < K; k0 += TILE_K) {
        s16x8 a0, a1;
        if (A_F32) {
            const float* s0 = Af + (size_t)r0 * lda + k0 + k80 * 8;
            a0 = cvt8(*(const f32x4*)s0, *(const f32x4*)(s0 + 4));
            const float* s1 = Af + (size_t)r1 * lda + k0 + k81 * 8;
            a1 = cvt8(*(const f32x4*)s1, *(const f32x4*)(s1 + 4));
        } else {
            a0 = *(const s16x8*)(Ab + (size_t)r0 * lda + k0 + k80 * 8);
            a1 = *(const s16x8*)(Ab + (size_t)r1 * lda + k0 + k81 * 8);
        }
        const float* t0 = Wp + (size_t)r0 * K + k0 + k80 * 8;
        s16x8 w0 = cvt8(*(const f32x4*)t0, *(const f32x4*)(t0 + 4));
        const float* t1 = Wp + (size_t)r1 * K + k0 + k81 * 8;
        s16x8 w1 = cvt8(*(const f32x4*)t1, *(const f32x4*)(t1 + 4));

        *(s16x8*)&sA[p0 * 8] = a0;
        *(s16x8*)&sA[p1 * 8] = a1;
        *(s16x8*)&sW[p0 * 8] = w0;
        *(s16x8*)&sW[p1 * 8] = w1;
        __syncthreads();

        bf16x8 af[4], wf[4];
#pragma unroll
        for (int i = 0; i < 4; ++i) {
            const int ar = wm + i * 16 + fc;
            af[i] = *(const bf16x8*)&sA[(ar * 4 + ((quad + (ar >> 1)) & 3)) * 8];
            const int wr = wn + i * 16 + fc;
            wf[i] = *(const bf16x8*)&sW[(wr * 4 + ((quad + (wr >> 1)) & 3)) * 8];
        }
#pragma unroll
        for (int i = 0; i < 4; ++i)
#pragma unroll
            for (int j = 0; j < 4; ++j)
                acc[i][j] = __builtin_amdgcn_mfma_f32_16x16x32_bf16(af[i], wf[j], acc[i][j], 0, 0, 0);
        __syncthreads();
    }

#pragma unroll
    for (int j = 0; j < 4; ++j) {
        const int col = bxl * TILE_N + wn + j * 16 + fc;
        const float bv = bias[wn + j * 16 + fc];
#pragma unroll
        for (int i = 0; i < 4; ++i) {
#pragma unroll
            for (int r = 0; r < 4; ++r) {
                const int row = by * TILE_M + wm + i * 16 + quad * 4 + r;
                const float v = acc[i][j][r] + bv;
                if (mode == 1)
                    ((float*)outv)[(size_t)row * ldo + col] = 1.0f / (1.0f + expf(-v));
                else
                    ((u16*)outv)[(size_t)row * ldo + col] = f2b(v);
            }
        }
    }
}

// comb[:,0:512]  = LN(n + o1)*n1_g + n1_b  (n = TN[:,512:], o1 = O[:,0:512])
// comb[:,512:]   = LN(t + o2)*n2_g + n2_b  (t = TN[:,0:512], o2 = O[:,512:])
// TN, O, comb bf16; gains/biases f32. One wave per 512-span.
__global__ __launch_bounds__(256)
void ln_stage1(const u16* __restrict__ TN, const u16* __restrict__ O,
               const float* __restrict__ g1, const float* __restrict__ b1,
               const float* __restrict__ g2, const float* __restrict__ b2,
               u16* __restrict__ comb)
{
    const int w = blockIdx.x * 4 + (threadIdx.x >> 6);
    const int lane = threadIdx.x & 63;
    const int row = w >> 1, half = w & 1;
    const u16* res = TN + (size_t)row * 1024 + (half ? 0 : 512);
    const u16* ov  = O  + (size_t)row * 1024 + (half ? 512 : 0);
    u16* out = comb + (size_t)row * 1024 + (half ? 512 : 0);
    const float* g = half ? g2 : g1;
    const float* b = half ? b2 : b1;
    const int c = lane * 8;

    s16x8 rv = *(const s16x8*)(res + c);
    s16x8 xv = *(const s16x8*)(ov + c);
    float x[8], s = 0.f, ss = 0.f;
#pragma unroll
    for (int j = 0; j < 8; ++j) {
        x[j] = b2f((u16)rv[j]) + b2f((u16)xv[j]);
        s += x[j]; ss += x[j] * x[j];
    }
#pragma unroll
    for (int m = 32; m >= 1; m >>= 1) { s += __shfl_xor(s, m, 64); ss += __shfl_xor(ss, m, 64); }
    const float mean = s * (1.f / 512.f);
    const float var = ss * (1.f / 512.f) - mean * mean;
    const float rs = rsqrtf(var + 1e-5f);
    s16x8 y;
#pragma unroll
    for (int j = 0; j < 8; ++j)
        y[j] = (short)f2b((x[j] - mean) * rs * g[c + j] + b[c + j]);
    *(s16x8*)(out + c) = y;
}

// h = gelu(LN(X)*g + b), span 512, bf16 in/out, one wave per row
__global__ __launch_bounds__(256)
void ln_gelu512(const u16* __restrict__ X, const float* __restrict__ g,
                const float* __restrict__ b, u16* __restrict__ out)
{
    const int row = blockIdx.x * 4 + (threadIdx.x >> 6);
    const int lane = threadIdx.x & 63;
    const int c = lane * 8;
    s16x8 xv = *(const s16x8*)(X + (size_t)row * 512 + c);
    float x[8], s = 0.f, ss = 0.f;
#pragma unroll
    for (int j = 0; j < 8; ++j) { x[j] = b2f((u16)xv[j]); s += x[j]; ss += x[j] * x[j]; }
#pragma unroll
    for (int m = 32; m >= 1; m >>= 1) { s += __shfl_xor(s, m, 64); ss += __shfl_xor(ss, m, 64); }
    const float mean = s * (1.f / 512.f);
    const float var = ss * (1.f / 512.f) - mean * mean;
    const float rs = rsqrtf(var + 1e-5f);
    s16x8 y;
#pragma unroll
    for (int j = 0; j < 8; ++j)
        y[j] = (short)f2b(gelu_f((x[j] - mean) * rs * g[c + j] + b[c + j]));
    *(s16x8*)(out + (size_t)row * 512 + c) = y;
}

// fused = gelu(LN(Z)*g + b), span 256, bf16 in, f32 out to d_out; attn = 1.0f
__global__ __launch_bounds__(256)
void ln_gelu256_out(const u16* __restrict__ Z, const float* __restrict__ g,
                    const float* __restrict__ b, float* __restrict__ dout)
{
    const int row = blockIdx.x * 4 + (threadIdx.x >> 6);
    const int lane = threadIdx.x & 63;
    const int c = lane * 4;
    s16x4 xv = *(const s16x4*)(Z + (size_t)row * 256 + c);
    float x[4], s = 0.f, ss = 0.f;
#pragma unroll
    for (int j = 0; j < 4; ++j) { x[j] = b2f((u16)xv[j]); s += x[j]; ss += x[j] * x[j]; }
#pragma unroll
    for (int m = 32; m >= 1; m >>= 1) { s += __shfl_xor(s, m, 64); ss += __shfl_xor(ss, m, 64); }
    const float mean = s * (1.f / 256.f);
    const float var = ss * (1.f / 256.f) - mean * mean;
    const float rs = rsqrtf(var + 1e-5f);
    f32x4 y;
#pragma unroll
    for (int j = 0; j < 4; ++j)
        y[j] = gelu_f((x[j] - mean) * rs * g[c + j] + b[c + j]);
    *(f32x4*)(dout + (size_t)row * 256 + c) = y;
    if (lane == 0) {
        dout[(size_t)16384 * 768 + row] = 1.0f;   // attn_n2t
        dout[(size_t)16384 * 769 + row] = 1.0f;   // attn_t2n
    }
}

extern "C" void kernel_launch(void* const* d_in, const int* in_sizes, int n_in,
                              void* d_out, int out_size, void* d_ws, size_t ws_size,
                              hipStream_t stream)
{
    const float* text  = (const float*)d_in[0];
    const float* num   = (const float*)d_in[1];
    const float* tp_w  = (const float*)d_in[2];
    const float* tp_b  = (const float*)d_in[3];
    const float* np_w  = (const float*)d_in[4];
    const float* np_b  = (const float*)d_in[5];
    const float* a1_wv = (const float*)d_in[8];
    const float* a1_bv = (const float*)d_in[11];
    const float* a1_wo = (const float*)d_in[12];
    const float* a1_bo = (const float*)d_in[13];
    const float* a2_wv = (const float*)d_in[16];
    const float* a2_bv = (const float*)d_in[19];
    const float* a2_wo = (const float*)d_in[20];
    const float* a2_bo = (const float*)d_in[21];
    const float* n1_g  = (const float*)d_in[22];
    const float* n1_b  = (const float*)d_in[23];
    const float* n2_g  = (const float*)d_in[24];
    const float* n2_b  = (const float*)d_in[25];
    const float* g_w   = (const float*)d_in[26];
    const float* g_b   = (const float*)d_in[27];
    const float* m1_w  = (const float*)d_in[28];
    const float* m1_b  = (const float*)d_in[29];
    const float* ln1_g = (const float*)d_in[30];
    const float* ln1_b = (const float*)d_in[31];
    const float* m2_w  = (const float*)d_in[32];
    const float* m2_b  = (const float*)d_in[33];
    const float* ln2_g = (const float*)d_in[34];
    const float* ln2_b = (const float*)d_in[35];

    float* outp = (float*)d_out;
    char* ws = (char*)d_ws;
    const size_t MB = 1048576;
    // bf16 activations. ws usage capped at 64 MB; O-scratch lives in d_out's
    // gate byte range [16MB,48MB) which is dead until K5 writes gate (f32).
    u16* TN   = (u16*)(ws);                    // [B,1024] bf16 (32 MB)  [t|n]
    u16* V    = (u16*)(ws + 32 * MB);          // [B,1024] bf16 (32 MB)  [v1|v2]
    u16* Obuf = (u16*)((char*)d_out + 16 * MB);// [B,1024] bf16 (32 MB)  [o1|o2]
    u16* comb = V;                             // V dead after K3
    u16* Y2   = (u16*)(ws);                    // [B,512] bf16 (16 MB); TN dead after L1
    u16* h    = (u16*)(ws + 16 * MB);          // [B,512] bf16 (16 MB)
    u16* Z    = (u16*)(ws + 32 * MB);          // [B,256] bf16 (8 MB); comb dead after K5

    const size_t B = 16384;
    dim3 blk(256);

    // K1: t = text@tp_w.T+tp_b ; n = num@np_w.T+np_b   (A is f32)
    gemm_bt<1><<<dim3(8, 128), blk, 0, stream>>>(text, num, tp_w, np_w, tp_b, np_b,
        TN, TN + 512, 256, 256, 4, 1024, 1024, 0, 0);
    // K2: v1 = t@a1_wv.T+a1_bv ; v2 = n@a2_wv.T+a2_bv
    gemm_bt<0><<<dim3(8, 128), blk, 0, stream>>>(TN, TN + 512, a1_wv, a2_wv, a1_bv, a2_bv,
        V, V + 512, 1024, 512, 4, 1024, 1024, 0, 0);
    // K3: o1 = v1@a1_wo.T+a1_bo ; o2 = v2@a2_wo.T+a2_bo
    gemm_bt<0><<<dim3(8, 128), blk, 0, stream>>>(V, V + 512, a1_wo, a2_wo, a1_bo, a2_bo,
        Obuf, Obuf + 512, 1024, 512, 4, 1024, 1024, 0, 0);
    // L1: comb = [LN(n+o1), LN(t+o2)]
    ln_stage1<<<8192, blk, 0, stream>>>(TN, Obuf, n1_g, n1_b, n2_g, n2_b, comb);
    // K5: gate = sigmoid(comb@g_w.T+g_b) -> d_out (f32) ; Y2 = comb@m1_w.T+m1_b (bf16)
    gemm_bt<0><<<dim3(8, 128), blk, 0, stream>>>(comb, comb, g_w, m1_w, g_b, m1_b,
        outp + B * 256, Y2, 1024, 1024, 4, 512, 512, 1, 0);
    // L2: h = gelu(LN(Y2)*ln1_g+ln1_b)
    ln_gelu512<<<4096, blk, 0, stream>>>(Y2, ln1_g, ln1_b, h);
    // K7: Z = h@m2_w.T+m2_b
    gemm_bt<0><<<dim3(2, 128), blk, 0, stream>>>(h, h, m2_w, m2_w, m2_b, m2_b,
        Z, Z, 512, 512, 2, 256, 256, 0, 0);
    // L3: fused = gelu(LN(Z)*ln2_g+ln2_b) -> d_out; attn outputs = 1.0f
    ln_gelu256_out<<<4096, blk, 0, stream>>>(Z, ln2_g, ln2_b, outp);
}